// Round 4
// baseline (1505.207 us; speedup 1.0000x reference)
//
#include <hip/hip_runtime.h>
#include <hip/hip_fp16.h>

#define NDIM 64
#define RS 68       // LDS row stride in floats
#define MAXB 2048   // max 64-node buckets: supports N <= 131072; here N=100000 -> 1563
#define CAPB 1472   // padded per-bucket capacity (mean 768, +25 sigma)
#define EB 1472     // per-block LDS edge buffer (= CAPB)

typedef _Float16 h4 __attribute__((ext_vector_type(4)));
typedef float f4v __attribute__((ext_vector_type(4)));

// ---------------- prep: BN-fold + split-fp16 weight pack, and x -> fp16 ----------------
// Wpk layout: [(l*2+m)][frag=ks*4+ct][lane][0..3]=hi j, [4..7]=lo j (halfs)
// frag element: k = ks*16 + (lane>>4)*4 + j, col = ct*16 + (lane&15)
__global__ __launch_bounds__(256) void prep_kernel(
    const float* __restrict__ x, __half* __restrict__ x16, int n4,
    const float* __restrict__ W1, const float* __restrict__ b1,
    const float* __restrict__ gamma, const float* __restrict__ beta,
    const float* __restrict__ mean, const float* __restrict__ var,
    const float* __restrict__ W2,
    _Float16* __restrict__ Wpk, float* __restrict__ b1f, int L)
{
    int bid = blockIdx.x;
    int t = threadIdx.x;
    if (bid < 2 * L) {
        int l = bid >> 1, m = bid & 1;
        const float* Wsrc = (m == 0 ? W1 : W2) + (size_t)l * 4096;
        if (m == 0 && t < 64) {
            float s = gamma[l * 64 + t] * rsqrtf(var[l * 64 + t] + 1e-5f);
            b1f[l * 64 + t] = (b1[l * 64 + t] - mean[l * 64 + t]) * s + beta[l * 64 + t];
        }
        int lane = t & 63;
        int c16 = lane & 15, kq = lane >> 4;
        for (int it = 0; it < 4; ++it) {
            int frag = it * 4 + (t >> 6);
            int ks = frag >> 2, ct = frag & 3;
            int col = ct * 16 + c16;
            int k0 = ks * 16 + kq * 4;
            float s = 1.f;
            if (m == 0) s = gamma[l * 64 + col] * rsqrtf(var[l * 64 + col] + 1e-5f);
            _Float16* dstp = Wpk + (((size_t)(l * 2 + m) * 16 + frag) * 64 + lane) * 8;
            for (int j = 0; j < 4; ++j) {
                float wv = Wsrc[(size_t)(k0 + j) * 64 + col] * s;
                _Float16 hi = (_Float16)wv;
                dstp[j] = hi;
                dstp[4 + j] = (_Float16)(wv - (float)hi);
            }
        }
        return;
    }
    int tid = (bid - 2 * L) * 256 + t;
    if (tid >= n4) return;
    float4 v = *(const float4*)(x + (size_t)tid * 4);
    __half2* dp = (__half2*)(x16 + (size_t)tid * 4);
    dp[0] = __floats2half2_rn(v.x, v.y);
    dp[1] = __floats2half2_rn(v.z, v.w);
}

// ------- single-pass scatter into padded per-block(64-node) regions, row-tagged -------
__global__ __launch_bounds__(256) void block_scatter_kernel(
    const int* __restrict__ src, const int* __restrict__ dst,
    int* __restrict__ bcnt, unsigned int* __restrict__ packed, int E, int NBB)
{
    __shared__ int hist[MAXB];
    __shared__ int sbase[MAXB];
    for (int i = threadIdx.x; i < NBB; i += 256) hist[i] = 0;
    __syncthreads();
    int start = blockIdx.x * blockDim.x + threadIdx.x;
    int stride = gridDim.x * blockDim.x;
    for (int e = start; e < E; e += stride)
        atomicAdd(&hist[dst[e] >> 6], 1);          // LDS atomic: on-CU
    __syncthreads();
    for (int i = threadIdx.x; i < NBB; i += 256) {
        int v = hist[i];
        sbase[i] = v ? (i * CAPB + atomicAdd(&bcnt[i], v)) : 0;
    }
    __syncthreads();
    for (int i = threadIdx.x; i < NBB; i += 256) hist[i] = 0;  // reuse as cursor
    __syncthreads();
    for (int e = start; e < E; e += stride) {
        int d = dst[e];
        int b = d >> 6;
        int r = atomicAdd(&hist[b], 1);            // LDS rank
        int pos = sbase[b] + r;
        if (pos < (b + 1) * CAPB)                  // overflow guard (never at +25 sigma)
            packed[pos] = (unsigned)src[e] | ((unsigned)(d & 63) << 26);
    }
}

// ---------------- fused GIN layer: edge-parallel gather + MFMA MLP ----------------
__device__ inline float4 load_h4(const __half* __restrict__ h, size_t row, int q) {
    uint2 u = *(const uint2*)(h + row * NDIM + q * 4);   // single 8B load
    __half2 a = __builtin_bit_cast(__half2, u.x);
    __half2 b = __builtin_bit_cast(__half2, u.y);
    float2 fa = __half22float2(a), fb = __half22float2(b);
    return make_float4(fa.x, fa.y, fb.x, fb.y);
}

__global__ __launch_bounds__(256, 7) void gin_layer_kernel(
    const __half* __restrict__ hin, __half* __restrict__ hout,
    float* __restrict__ jk,
    const int* __restrict__ bcnt, const unsigned int* __restrict__ packed,
    const _Float16* __restrict__ w1p, const _Float16* __restrict__ w2p,
    const float* __restrict__ b1f, const float* __restrict__ b2,
    int N, int relu_out, int first, int write_h)
{
    __shared__ float lds[64 * RS];       // 17408B: block tile, reused pre->z->h
    __shared__ unsigned int ebuf[EB];    // 5888B: edge slice prefetch
    int t = threadIdx.x;
    int lane = t & 63;
    int w = t >> 6;
    int row0 = blockIdx.x * 64;

    int C = bcnt[blockIdx.x];
    if (C > CAPB) C = CAPB;
    const unsigned int* gpk = packed + (size_t)blockIdx.x * CAPB;
    bool useLds = (C <= EB);

    // ---- stage edge slice (coalesced) + init tile with self rows ----
    if (useLds)
        for (int k = t; k < C; k += 256) ebuf[k] = gpk[k];
    #pragma unroll
    for (int it = 0; it < 4; ++it) {
        int c = it * 256 + t;
        int r = c >> 4, q = c & 15;
        int node = row0 + r;
        float4 v = (node < N) ? load_h4(hin, (size_t)node, q)
                              : make_float4(0.f, 0.f, 0.f, 0.f);
        float* p = lds + r * RS + q * 4;
        p[0] = v.x; p[1] = v.y; p[2] = v.z; p[3] = v.w;
    }
    __syncthreads();

    // ---- edge-parallel gather: 16 groups x 16 lanes, branch-free stride loop ----
    {
        int gid = t >> 4;      // group 0..15 handles edges gid, gid+16, ...
        int q = t & 15;        // 8B chunk of the 128B row
        auto body = [&](int k) {
            unsigned u = useLds ? ebuf[k] : gpk[k];
            int r = (int)(u >> 26);
            int idx = (int)(u & 0x03FFFFFFu);
            float4 v = load_h4(hin, (size_t)idx, q);
            float* dp = lds + r * RS + q * 4;
            atomicAdd(dp + 0, v.x);                // ds_add_f32, fire-and-forget
            atomicAdd(dp + 1, v.y);
            atomicAdd(dp + 2, v.z);
            atomicAdd(dp + 3, v.w);
        };
        int k = gid;
        for (; k + 16 < C; k += 32) { body(k); body(k + 16); }
        if (k < C) body(k);
    }
    __syncthreads();

    // ---- MLP via MFMA, split-fp16 for ~fp32 accuracy (wave owns rows w*16..+15) ----
    // A: row=lane&15, k=4*(lane>>4)+j (+16*ks); B: col=lane&15, same k
    // C: row=(lane>>4)*4+reg, col=lane&15
    int lane15 = lane & 15;
    int lgrp = lane >> 4;
    int wrow0 = row0 + w * 16;
    float* wtile = lds + (size_t)w * 16 * RS;
    const float* aRow = wtile + (size_t)lane15 * RS;
    const h4* W1 = (const h4*)w1p;
    const h4* W2 = (const h4*)w2p;
    f4v zero = {0.f, 0.f, 0.f, 0.f};
    f4v acc[4];

    // GEMM1: z = relu(pre @ W1f + b1f)
    #pragma unroll
    for (int ct = 0; ct < 4; ++ct) acc[ct] = zero;
    #pragma unroll
    for (int ks = 0; ks < 4; ++ks) {
        float4 av = *(const float4*)(aRow + ks * 16 + lgrp * 4);
        h4 ah, al;
        ah[0] = (_Float16)av.x; al[0] = (_Float16)(av.x - (float)ah[0]);
        ah[1] = (_Float16)av.y; al[1] = (_Float16)(av.y - (float)ah[1]);
        ah[2] = (_Float16)av.z; al[2] = (_Float16)(av.z - (float)ah[2]);
        ah[3] = (_Float16)av.w; al[3] = (_Float16)(av.w - (float)ah[3]);
        #pragma unroll
        for (int ct = 0; ct < 4; ++ct) {
            const h4* bp = W1 + (size_t)((ks * 4 + ct) * 64 + lane) * 2;
            h4 bh = bp[0], bl = bp[1];   // one dwordx4
            acc[ct] = __builtin_amdgcn_mfma_f32_16x16x16f16(ah, bh, acc[ct], 0, 0, 0);
            acc[ct] = __builtin_amdgcn_mfma_f32_16x16x16f16(al, bh, acc[ct], 0, 0, 0);
            acc[ct] = __builtin_amdgcn_mfma_f32_16x16x16f16(ah, bl, acc[ct], 0, 0, 0);
        }
    }
    asm volatile("" ::: "memory");
    #pragma unroll
    for (int ct = 0; ct < 4; ++ct) {
        int col = ct * 16 + lane15;
        float bb = b1f[col];
        #pragma unroll
        for (int i = 0; i < 4; ++i)
            wtile[(size_t)(lgrp * 4 + i) * RS + col] = fmaxf(acc[ct][i] + bb, 0.f);
    }
    asm volatile("" ::: "memory");

    // GEMM2: h = z @ W2 + b2 (+relu for non-final layers)
    #pragma unroll
    for (int ct = 0; ct < 4; ++ct) acc[ct] = zero;
    #pragma unroll
    for (int ks = 0; ks < 4; ++ks) {
        float4 av = *(const float4*)(aRow + ks * 16 + lgrp * 4);
        h4 ah, al;
        ah[0] = (_Float16)av.x; al[0] = (_Float16)(av.x - (float)ah[0]);
        ah[1] = (_Float16)av.y; al[1] = (_Float16)(av.y - (float)ah[1]);
        ah[2] = (_Float16)av.z; al[2] = (_Float16)(av.z - (float)ah[2]);
        ah[3] = (_Float16)av.w; al[3] = (_Float16)(av.w - (float)ah[3]);
        #pragma unroll
        for (int ct = 0; ct < 4; ++ct) {
            const h4* bp = W2 + (size_t)((ks * 4 + ct) * 64 + lane) * 2;
            h4 bh = bp[0], bl = bp[1];
            acc[ct] = __builtin_amdgcn_mfma_f32_16x16x16f16(ah, bh, acc[ct], 0, 0, 0);
            acc[ct] = __builtin_amdgcn_mfma_f32_16x16x16f16(al, bh, acc[ct], 0, 0, 0);
            acc[ct] = __builtin_amdgcn_mfma_f32_16x16x16f16(ah, bl, acc[ct], 0, 0, 0);
        }
    }
    asm volatile("" ::: "memory");
    #pragma unroll
    for (int ct = 0; ct < 4; ++ct) {
        int col = ct * 16 + lane15;
        float bb = b2[col];
        #pragma unroll
        for (int i = 0; i < 4; ++i) {
            float hv = acc[ct][i] + bb;
            if (relu_out) hv = fmaxf(hv, 0.f);
            wtile[(size_t)(lgrp * 4 + i) * RS + col] = hv;
        }
    }
    asm volatile("" ::: "memory");

    // ---- writeback: wave-local (16 rows x 16 f4-chunks = 256 chunks / 64 lanes) ----
    #pragma unroll
    for (int it = 0; it < 4; ++it) {
        int fl = it * 64 + lane;
        int r = fl >> 4, c4 = fl & 15;
        int grow = wrow0 + r;
        if (grow >= N) continue;
        const float* p = wtile + (size_t)r * RS + c4 * 4;
        float4 hv = make_float4(p[0], p[1], p[2], p[3]);
        if (write_h) {
            __half2* dp = (__half2*)(hout + (size_t)grow * NDIM + c4 * 4);
            dp[0] = __floats2half2_rn(hv.x, hv.y);
            dp[1] = __floats2half2_rn(hv.z, hv.w);
        }
        float4 jv;
        if (first) jv = hv;
        else {
            float4 o = *(const float4*)(jk + (size_t)grow * NDIM + c4 * 4);
            jv = make_float4(o.x + hv.x, o.y + hv.y, o.z + hv.z, o.w + hv.w);
        }
        *(float4*)(jk + (size_t)grow * NDIM + c4 * 4) = jv;
    }
}

extern "C" void kernel_launch(void* const* d_in, const int* in_sizes, int n_in,
                              void* d_out, int out_size, void* d_ws, size_t ws_size,
                              hipStream_t stream) {
    const float* x     = (const float*)d_in[0];
    const int*   src   = (const int*)  d_in[1];
    const int*   dst   = (const int*)  d_in[2];
    const float* W1    = (const float*)d_in[3];
    const float* b1    = (const float*)d_in[4];
    const float* gamma = (const float*)d_in[5];
    const float* beta  = (const float*)d_in[6];
    const float* mean  = (const float*)d_in[7];
    const float* var   = (const float*)d_in[8];
    const float* W2    = (const float*)d_in[9];
    const float* b2    = (const float*)d_in[10];

    int N = in_sizes[0] / NDIM;
    int E = in_sizes[1];
    int L = in_sizes[3] / (NDIM * NDIM);
    int NBB = (N + 63) >> 6;             // buckets of 64 nodes = one per gin block
    int n4 = N * NDIM / 4;
    float* out = (float*)d_out;

    char* w = (char*)d_ws;
    size_t off = 0;
    auto carve = [&](size_t bytes) -> void* {
        void* p = w + off;
        off += (bytes + 255) & ~(size_t)255;
        return p;
    };
    __half* h16A    = (__half*)carve((size_t)N * NDIM * 2);   // ping
    __half* h16B    = (__half*)carve((size_t)N * NDIM * 2);   // pong
    unsigned int* packed = (unsigned int*)carve((size_t)NBB * CAPB * 4);
    int*    bcnt    = (int*)   carve((size_t)(NBB + 1) * 4);
    _Float16* Wpk   = (_Float16*)carve((size_t)L * 2 * 16 * 64 * 8 * 2);  // hi/lo packed frags
    float*  b1f     = (float*) carve((size_t)L * NDIM * 4);

    hipMemsetAsync(bcnt, 0, (size_t)(NBB + 1) * 4, stream);
    prep_kernel<<<2 * L + (n4 + 255) / 256, 256, 0, stream>>>(
        x, h16A, n4, W1, b1, gamma, beta, mean, var, W2, Wpk, b1f, L);
    block_scatter_kernel<<<128, 256, 0, stream>>>(src, dst, bcnt, packed, E, NBB);

    const __half* hin = h16A;
    __half* hout = h16B;
    for (int l = 0; l < L; ++l) {
        gin_layer_kernel<<<NBB, 256, 0, stream>>>(
            hin, hout, out, bcnt, packed,
            Wpk + (size_t)(l * 2 + 0) * 16 * 64 * 8,
            Wpk + (size_t)(l * 2 + 1) * 16 * 64 * 8,
            b1f + (size_t)l * NDIM, b2 + (size_t)l * NDIM,
            N, (l < L - 1) ? 1 : 0, (l == 0) ? 1 : 0, (l < L - 1) ? 1 : 0);
        const __half* tmp = hin;
        hin = hout;
        hout = (__half*)tmp;
    }
}

// Round 5
// 250.381 us; speedup vs baseline: 6.0117x; 6.0117x over previous
//
#include <hip/hip_runtime.h>
#include <hip/hip_fp16.h>

#define NDIM 64
#define RS 68      // LDS row stride in floats: 16B-aligned rows, conflict-free b128 frag reads
#define MAXNB 512  // supports N <= 131072 (bucket = dst>>8); this problem: N=100000 -> 391
#define CAP 6144   // padded per-bucket capacity (expected ~3072, +55 sigma headroom)
#define EBUF 352   // per-wave LDS edge-index buffer (16 rows, mean 192 edges, +11 sigma)

typedef _Float16 h4 __attribute__((ext_vector_type(4)));
typedef float f4v __attribute__((ext_vector_type(4)));

// ---------------- prep: BN-fold + split-fp16 weight pack, and x -> fp16 ----------------
// Wpk layout: [(l*2+m)][frag=ks*4+ct][lane][0..3]=hi j, [4..7]=lo j (halfs)
// frag element: k = ks*16 + (lane>>4)*4 + j, col = ct*16 + (lane&15)
__global__ __launch_bounds__(256) void prep_kernel(
    const float* __restrict__ x, __half* __restrict__ x16, int n4,
    const float* __restrict__ W1, const float* __restrict__ b1,
    const float* __restrict__ gamma, const float* __restrict__ beta,
    const float* __restrict__ mean, const float* __restrict__ var,
    const float* __restrict__ W2,
    _Float16* __restrict__ Wpk, float* __restrict__ b1f, int L)
{
    int bid = blockIdx.x;
    int t = threadIdx.x;
    if (bid < 2 * L) {
        int l = bid >> 1, m = bid & 1;
        const float* Wsrc = (m == 0 ? W1 : W2) + (size_t)l * 4096;
        if (m == 0 && t < 64) {
            float s = gamma[l * 64 + t] * rsqrtf(var[l * 64 + t] + 1e-5f);
            b1f[l * 64 + t] = (b1[l * 64 + t] - mean[l * 64 + t]) * s + beta[l * 64 + t];
        }
        int lane = t & 63;
        int c16 = lane & 15, kq = lane >> 4;
        for (int it = 0; it < 4; ++it) {
            int frag = it * 4 + (t >> 6);
            int ks = frag >> 2, ct = frag & 3;
            int col = ct * 16 + c16;
            int k0 = ks * 16 + kq * 4;
            float s = 1.f;
            if (m == 0) s = gamma[l * 64 + col] * rsqrtf(var[l * 64 + col] + 1e-5f);
            _Float16* dstp = Wpk + (((size_t)(l * 2 + m) * 16 + frag) * 64 + lane) * 8;
            for (int j = 0; j < 4; ++j) {
                float wv = Wsrc[(size_t)(k0 + j) * 64 + col] * s;
                _Float16 hi = (_Float16)wv;
                dstp[j] = hi;
                dstp[4 + j] = (_Float16)(wv - (float)hi);
            }
        }
        return;
    }
    int tid = (bid - 2 * L) * 256 + t;
    if (tid >= n4) return;
    float4 v = *(const float4*)(x + (size_t)tid * 4);
    __half2* dp = (__half2*)(x16 + (size_t)tid * 4);
    dp[0] = __floats2half2_rn(v.x, v.y);
    dp[1] = __floats2half2_rn(v.z, v.w);
}

// ---------------- single-pass bucket scatter into padded regions ----------------
__global__ __launch_bounds__(256) void bucket_scatter_kernel(
    const int* __restrict__ src, const int* __restrict__ dst,
    int* __restrict__ bcnt, unsigned int* __restrict__ packed, int E, int NBb)
{
    __shared__ int hist[MAXNB];
    __shared__ int sbase[MAXNB];
    for (int i = threadIdx.x; i < NBb; i += 256) hist[i] = 0;
    __syncthreads();
    int start = blockIdx.x * blockDim.x + threadIdx.x;
    int stride = gridDim.x * blockDim.x;
    for (int e = start; e < E; e += stride)
        atomicAdd(&hist[dst[e] >> 8], 1);          // LDS int atomic: native, on-CU
    __syncthreads();
    for (int i = threadIdx.x; i < NBb; i += 256) {
        int v = hist[i];
        sbase[i] = v ? (i * CAP + atomicAdd(&bcnt[i], v)) : 0;
    }
    __syncthreads();
    for (int i = threadIdx.x; i < NBb; i += 256) hist[i] = 0;  // reuse as cursor
    __syncthreads();
    for (int e = start; e < E; e += stride) {
        int d = dst[e];
        int b = d >> 8;
        int r = atomicAdd(&hist[b], 1);            // LDS rank
        packed[sbase[b] + r] = (unsigned)src[e] | ((unsigned)(d & 255) << 24);
    }
}

// ---------------- per-bucket CSR finalize (inline exclusive prefix of bcnt) ----------------
__global__ __launch_bounds__(256) void bucket_csr_kernel(
    const unsigned int* __restrict__ packed, const int* __restrict__ bcnt,
    int* __restrict__ ssrc, int* __restrict__ offs, int* __restrict__ ends, int N)
{
    __shared__ int hist[256], scan[256], cur[256];
    __shared__ int swbase;
    int b = blockIdx.x;
    int t = threadIdx.x;
    // exclusive prefix: wbase = sum_{i<b} bcnt[i]
    int partial = 0;
    for (int i = t; i < b; i += 256) partial += bcnt[i];
    scan[t] = partial;
    hist[t] = 0;
    __syncthreads();
    for (int d = 128; d > 0; d >>= 1) {
        if (t < d) scan[t] += scan[t + d];
        __syncthreads();
    }
    if (t == 0) swbase = scan[0];
    __syncthreads();
    int wbase = swbase;
    int cnt = bcnt[b];
    if (cnt > CAP) cnt = CAP;
    size_t rbase = (size_t)b * CAP;
    for (int i = t; i < cnt; i += 256)
        atomicAdd(&hist[packed[rbase + i] >> 24], 1);
    __syncthreads();
    int v = hist[t];
    scan[t] = v;
    __syncthreads();
    for (int d = 1; d < 256; d <<= 1) {
        int x = scan[t];
        int y = (t >= d) ? scan[t - d] : 0;
        __syncthreads();
        scan[t] = x + y;
        __syncthreads();
    }
    int e0 = wbase + scan[t] - v;
    cur[t] = e0;
    int node = b * 256 + t;
    if (node < N) { offs[node] = e0; ends[node] = e0 + v; }
    __syncthreads();
    for (int i = t; i < cnt; i += 256) {
        unsigned p = packed[rbase + i];
        int pos = atomicAdd(&cur[p >> 24], 1);
        ssrc[pos] = (int)(p & 0xFFFFFF);
    }
}

// ---------------- fused GIN layer: barrier-free, wave-owns-16-rows ----------------
__device__ inline void add4(float4& a, const float4& v) {
    a.x += v.x; a.y += v.y; a.z += v.z; a.w += v.w;
}

// accumulate 8 halves (16B) into two float4 accumulators
__device__ inline void cvt_acc(uint4 u, float4& a0, float4& a1) {
    __half2 h0 = __builtin_bit_cast(__half2, u.x);
    __half2 h1 = __builtin_bit_cast(__half2, u.y);
    __half2 h2 = __builtin_bit_cast(__half2, u.z);
    __half2 h3 = __builtin_bit_cast(__half2, u.w);
    float2 f0 = __half22float2(h0), f1 = __half22float2(h1);
    float2 f2 = __half22float2(h2), f3 = __half22float2(h3);
    a0.x += f0.x; a0.y += f0.y; a0.z += f1.x; a0.w += f1.y;
    a1.x += f2.x; a1.y += f2.y; a1.z += f3.x; a1.w += f3.y;
}

__global__ __launch_bounds__(256, 7) void gin_layer_kernel(
    const __half* __restrict__ hin, __half* __restrict__ hout,
    float* __restrict__ jk,
    const int* __restrict__ offs, const int* __restrict__ ends,
    const int* __restrict__ ssrc,
    const _Float16* __restrict__ w1p, const _Float16* __restrict__ w2p,
    const float* __restrict__ b1f, const float* __restrict__ b2,
    int N, int relu_out, int first, int write_h)
{
    __shared__ float lds[64 * RS];       // 17408B: per-wave 16-row tile, reused pre->z->h
    __shared__ int ebuf_s[4 * EBUF];     // 5632B: per-wave edge-index prefetch
    int t = threadIdx.x;
    int lane = t & 63;
    int w = t >> 6;
    int row0 = blockIdx.x * 64;
    int wrow0 = row0 + w * 16;           // this wave's 16 rows
    if (wrow0 >= N) return;              // legal: no barriers anywhere in this kernel

    float* wtile = lds + (size_t)w * 16 * RS;
    int* ebuf = ebuf_s + w * EBUF;

    // ---- per-wave CSR offsets via shuffle broadcast (no sync) ----
    int offv = 0, endv = 0;
    if (lane < 16) {
        int node = wrow0 + lane;
        int cn = (node < N) ? node : (N - 1);
        offv = offs[cn];
        endv = ends[cn];
        if (node >= N) offv = endv;      // OOB rows -> empty
    }
    int begAll = __shfl(offv, 0, 64);
    int endAll = __shfl(endv, 15, 64);
    int cnt = endAll - begAll;

    // ---- jk prefetch: issue early, latency hides under the gather ----
    float4 jpre[4];
    #pragma unroll
    for (int it = 0; it < 4; ++it) jpre[it] = make_float4(0.f, 0.f, 0.f, 0.f);
    if (!first) {
        #pragma unroll
        for (int it = 0; it < 4; ++it) {
            int fl = it * 64 + lane;
            int r = fl >> 4, c4 = fl & 15;
            int grow = wrow0 + r;
            if (grow < N)
                jpre[it] = *(const float4*)(jk + (size_t)grow * NDIM + c4 * 4);
        }
    }

    // ---- prefetch this wave's contiguous edge-index slice into LDS (coalesced) ----
    bool useLds = (cnt <= EBUF);
    if (useLds) {
        for (int k = lane; k < cnt; k += 64) ebuf[k] = ssrc[begAll + k];
    }
    asm volatile("" ::: "memory");       // compiler fence; same-wave DS is in-order in HW
    auto eidx = [&](int pos) -> int {
        return useLds ? ebuf[pos - begAll] : ssrc[pos];
    };

    // ---- gather: 8 rows concurrently; lane = (row-slot, 16B chunk); no reduce ----
    int rslot = lane >> 3;   // 0..7: row within the 8-row group
    int q = lane & 7;        // 16B chunk of the 128B row (8 halves)
    #pragma unroll
    for (int i = 0; i < 2; ++i) {
        int rsel = i * 8 + rslot;
        int node = wrow0 + rsel;
        int beg = __shfl(offv, rsel, 64);
        int end = __shfl(endv, rsel, 64);

        float4 a0 = make_float4(0.f, 0.f, 0.f, 0.f);
        float4 a1 = make_float4(0.f, 0.f, 0.f, 0.f);
        float4 b0 = make_float4(0.f, 0.f, 0.f, 0.f);
        float4 b1v = make_float4(0.f, 0.f, 0.f, 0.f);
        if (node < N) {
            uint4 u = *(const uint4*)(hin + (size_t)node * NDIM + q * 8);
            cvt_acc(u, a0, a1);
        }
        int k = beg;
        for (; k + 2 <= end; k += 2) {          // counted, branch-light, pipelineable
            int i0 = eidx(k), i1 = eidx(k + 1);
            uint4 u0 = *(const uint4*)(hin + (size_t)i0 * NDIM + q * 8);
            uint4 u1 = *(const uint4*)(hin + (size_t)i1 * NDIM + q * 8);
            cvt_acc(u0, a0, a1);
            cvt_acc(u1, b0, b1v);
        }
        if (k < end) {
            uint4 u0 = *(const uint4*)(hin + (size_t)eidx(k) * NDIM + q * 8);
            cvt_acc(u0, a0, a1);
        }
        add4(a0, b0); add4(a1, b1v);
        if (node < N) {
            float* p = wtile + rsel * RS + q * 8;
            *(float4*)(p) = a0;
            *(float4*)(p + 4) = a1;
        }
    }
    asm volatile("" ::: "memory");   // phase fence (same-wave DS is in-order in HW)

    // ---- MLP via MFMA, split-fp16 for ~fp32 accuracy ----
    // A: row=lane&15, k=4*(lane>>4)+j (+16*ks); B: col=lane&15, same k
    // C: row=(lane>>4)*4+reg, col=lane&15
    int lane15 = lane & 15;
    int lgrp = lane >> 4;
    const float* aRow = wtile + (size_t)lane15 * RS;
    const h4* W1 = (const h4*)w1p;
    const h4* W2 = (const h4*)w2p;
    f4v zero = {0.f, 0.f, 0.f, 0.f};
    f4v acc[4];

    // GEMM1: z = relu(pre @ W1f + b1f)
    #pragma unroll
    for (int ct = 0; ct < 4; ++ct) acc[ct] = zero;
    #pragma unroll
    for (int ks = 0; ks < 4; ++ks) {
        float4 av = *(const float4*)(aRow + ks * 16 + lgrp * 4);
        h4 ah, al;
        ah[0] = (_Float16)av.x; al[0] = (_Float16)(av.x - (float)ah[0]);
        ah[1] = (_Float16)av.y; al[1] = (_Float16)(av.y - (float)ah[1]);
        ah[2] = (_Float16)av.z; al[2] = (_Float16)(av.z - (float)ah[2]);
        ah[3] = (_Float16)av.w; al[3] = (_Float16)(av.w - (float)ah[3]);
        #pragma unroll
        for (int ct = 0; ct < 4; ++ct) {
            const h4* bp = W1 + (size_t)((ks * 4 + ct) * 64 + lane) * 2;
            h4 bh = bp[0], bl = bp[1];   // one dwordx4
            acc[ct] = __builtin_amdgcn_mfma_f32_16x16x16f16(ah, bh, acc[ct], 0, 0, 0);
            acc[ct] = __builtin_amdgcn_mfma_f32_16x16x16f16(al, bh, acc[ct], 0, 0, 0);
            acc[ct] = __builtin_amdgcn_mfma_f32_16x16x16f16(ah, bl, acc[ct], 0, 0, 0);
        }
    }
    asm volatile("" ::: "memory");
    #pragma unroll
    for (int ct = 0; ct < 4; ++ct) {
        int col = ct * 16 + lane15;
        float bb = b1f[col];
        #pragma unroll
        for (int i = 0; i < 4; ++i)
            wtile[(size_t)(lgrp * 4 + i) * RS + col] = fmaxf(acc[ct][i] + bb, 0.f);
    }
    asm volatile("" ::: "memory");

    // GEMM2: h = z @ W2 + b2 (+relu for non-final layers)
    #pragma unroll
    for (int ct = 0; ct < 4; ++ct) acc[ct] = zero;
    #pragma unroll
    for (int ks = 0; ks < 4; ++ks) {
        float4 av = *(const float4*)(aRow + ks * 16 + lgrp * 4);
        h4 ah, al;
        ah[0] = (_Float16)av.x; al[0] = (_Float16)(av.x - (float)ah[0]);
        ah[1] = (_Float16)av.y; al[1] = (_Float16)(av.y - (float)ah[1]);
        ah[2] = (_Float16)av.z; al[2] = (_Float16)(av.z - (float)ah[2]);
        ah[3] = (_Float16)av.w; al[3] = (_Float16)(av.w - (float)ah[3]);
        #pragma unroll
        for (int ct = 0; ct < 4; ++ct) {
            const h4* bp = W2 + (size_t)((ks * 4 + ct) * 64 + lane) * 2;
            h4 bh = bp[0], bl = bp[1];
            acc[ct] = __builtin_amdgcn_mfma_f32_16x16x16f16(ah, bh, acc[ct], 0, 0, 0);
            acc[ct] = __builtin_amdgcn_mfma_f32_16x16x16f16(al, bh, acc[ct], 0, 0, 0);
            acc[ct] = __builtin_amdgcn_mfma_f32_16x16x16f16(ah, bl, acc[ct], 0, 0, 0);
        }
    }
    asm volatile("" ::: "memory");
    #pragma unroll
    for (int ct = 0; ct < 4; ++ct) {
        int col = ct * 16 + lane15;
        float bb = b2[col];
        #pragma unroll
        for (int i = 0; i < 4; ++i) {
            float hv = acc[ct][i] + bb;
            if (relu_out) hv = fmaxf(hv, 0.f);
            wtile[(size_t)(lgrp * 4 + i) * RS + col] = hv;
        }
    }
    asm volatile("" ::: "memory");

    // ---- writeback: wave-local (16 rows x 16 f4-chunks = 256 chunks / 64 lanes) ----
    #pragma unroll
    for (int it = 0; it < 4; ++it) {
        int fl = it * 64 + lane;
        int r = fl >> 4, c4 = fl & 15;
        int grow = wrow0 + r;
        if (grow >= N) continue;
        const float* p = wtile + (size_t)r * RS + c4 * 4;
        float4 hv = make_float4(p[0], p[1], p[2], p[3]);
        if (write_h) {
            __half2* dp = (__half2*)(hout + (size_t)grow * NDIM + c4 * 4);
            dp[0] = __floats2half2_rn(hv.x, hv.y);
            dp[1] = __floats2half2_rn(hv.z, hv.w);
        }
        float4 jv;
        if (first) jv = hv;
        else {
            float4 o = jpre[it];
            jv = make_float4(o.x + hv.x, o.y + hv.y, o.z + hv.z, o.w + hv.w);
        }
        *(float4*)(jk + (size_t)grow * NDIM + c4 * 4) = jv;
    }
}

extern "C" void kernel_launch(void* const* d_in, const int* in_sizes, int n_in,
                              void* d_out, int out_size, void* d_ws, size_t ws_size,
                              hipStream_t stream) {
    const float* x     = (const float*)d_in[0];
    const int*   src   = (const int*)  d_in[1];
    const int*   dst   = (const int*)  d_in[2];
    const float* W1    = (const float*)d_in[3];
    const float* b1    = (const float*)d_in[4];
    const float* gamma = (const float*)d_in[5];
    const float* beta  = (const float*)d_in[6];
    const float* mean  = (const float*)d_in[7];
    const float* var   = (const float*)d_in[8];
    const float* W2    = (const float*)d_in[9];
    const float* b2    = (const float*)d_in[10];

    int N = in_sizes[0] / NDIM;
    int E = in_sizes[1];
    int L = in_sizes[3] / (NDIM * NDIM);
    int NBb = (N + 255) >> 8;            // buckets of 256 nodes
    int n4 = N * NDIM / 4;
    float* out = (float*)d_out;

    char* w = (char*)d_ws;
    size_t off = 0;
    auto carve = [&](size_t bytes) -> void* {
        void* p = w + off;
        off += (bytes + 255) & ~(size_t)255;
        return p;
    };
    __half* h16A    = (__half*)carve((size_t)N * NDIM * 2);   // ping
    __half* h16B    = (__half*)carve((size_t)N * NDIM * 2);   // pong
    int*    ssrc    = (int*)   carve((size_t)E * 4);
    unsigned int* packed = (unsigned int*)carve((size_t)NBb * CAP * 4);
    int*    offs    = (int*)   carve((size_t)N * 4);
    int*    ends    = (int*)   carve((size_t)N * 4);
    int*    bcnt    = (int*)   carve((size_t)(MAXNB + 1) * 4);
    _Float16* Wpk   = (_Float16*)carve((size_t)L * 2 * 16 * 64 * 8 * 2);  // hi/lo packed frags
    float*  b1f     = (float*) carve((size_t)L * NDIM * 4);

    hipMemsetAsync(bcnt, 0, (size_t)(MAXNB + 1) * 4, stream);
    prep_kernel<<<2 * L + (n4 + 255) / 256, 256, 0, stream>>>(
        x, h16A, n4, W1, b1, gamma, beta, mean, var, W2, Wpk, b1f, L);
    bucket_scatter_kernel<<<256, 256, 0, stream>>>(src, dst, bcnt, packed, E, NBb);
    bucket_csr_kernel<<<NBb, 256, 0, stream>>>(packed, bcnt, ssrc, offs, ends, N);

    const __half* hin = h16A;
    __half* hout = h16B;
    for (int l = 0; l < L; ++l) {
        gin_layer_kernel<<<(N + 63) / 64, 256, 0, stream>>>(
            hin, hout, out, offs, ends, ssrc,
            Wpk + (size_t)(l * 2 + 0) * 16 * 64 * 8,
            Wpk + (size_t)(l * 2 + 1) * 16 * 64 * 8,
            b1f + (size_t)l * NDIM, b2 + (size_t)l * NDIM,
            N, (l < L - 1) ? 1 : 0, (l == 0) ? 1 : 0, (l < L - 1) ? 1 : 0);
        const __half* tmp = hin;
        hin = hout;
        hout = (__half*)tmp;
    }
}

// Round 6
// 244.442 us; speedup vs baseline: 6.1577x; 1.0243x over previous
//
#include <hip/hip_runtime.h>
#include <hip/hip_fp16.h>

#define NDIM 64
#define RS 68      // LDS row stride in floats: 16B-aligned rows, conflict-free b128 frag reads
#define MAXNB 512  // supports N <= 131072 (bucket = dst>>8); this problem: N=100000 -> 391
#define CAP 6144   // padded per-bucket capacity (expected ~3072, +55 sigma headroom)
#define EBUF 352   // per-wave LDS edge-index buffer (16 rows, mean 192 edges, +11 sigma)

typedef _Float16 h4 __attribute__((ext_vector_type(4)));
typedef float f4v __attribute__((ext_vector_type(4)));

// ---------------- prep: BN-fold + split-fp16 weight pack, x -> fp16, bcnt zero ----------------
// Wpk layout: [(l*2+m)][frag=ks*4+ct][lane][0..3]=hi j, [4..7]=lo j (halfs)
// frag element: k = ks*16 + (lane>>4)*4 + j, col = ct*16 + (lane&15)
__global__ __launch_bounds__(256) void prep_kernel(
    const float* __restrict__ x, __half* __restrict__ x16, int n4,
    const float* __restrict__ W1, const float* __restrict__ b1,
    const float* __restrict__ gamma, const float* __restrict__ beta,
    const float* __restrict__ mean, const float* __restrict__ var,
    const float* __restrict__ W2,
    _Float16* __restrict__ Wpk, float* __restrict__ b1f, int L,
    int* __restrict__ bcnt, int nbz)
{
    int bid = blockIdx.x;
    int t = threadIdx.x;
    if (bid < 2 * L) {
        if (bid == 0)
            for (int i = t; i < nbz; i += 256) bcnt[i] = 0;   // replaces hipMemsetAsync
        int l = bid >> 1, m = bid & 1;
        const float* Wsrc = (m == 0 ? W1 : W2) + (size_t)l * 4096;
        if (m == 0 && t < 64) {
            float s = gamma[l * 64 + t] * rsqrtf(var[l * 64 + t] + 1e-5f);
            b1f[l * 64 + t] = (b1[l * 64 + t] - mean[l * 64 + t]) * s + beta[l * 64 + t];
        }
        int lane = t & 63;
        int c16 = lane & 15, kq = lane >> 4;
        for (int it = 0; it < 4; ++it) {
            int frag = it * 4 + (t >> 6);
            int ks = frag >> 2, ct = frag & 3;
            int col = ct * 16 + c16;
            int k0 = ks * 16 + kq * 4;
            float s = 1.f;
            if (m == 0) s = gamma[l * 64 + col] * rsqrtf(var[l * 64 + col] + 1e-5f);
            _Float16* dstp = Wpk + (((size_t)(l * 2 + m) * 16 + frag) * 64 + lane) * 8;
            for (int j = 0; j < 4; ++j) {
                float wv = Wsrc[(size_t)(k0 + j) * 64 + col] * s;
                _Float16 hi = (_Float16)wv;
                dstp[j] = hi;
                dstp[4 + j] = (_Float16)(wv - (float)hi);
            }
        }
        return;
    }
    int tid = (bid - 2 * L) * 256 + t;
    if (tid >= n4) return;
    float4 v = *(const float4*)(x + (size_t)tid * 4);
    __half2* dp = (__half2*)(x16 + (size_t)tid * 4);
    dp[0] = __floats2half2_rn(v.x, v.y);
    dp[1] = __floats2half2_rn(v.z, v.w);
}

// ---------------- single-pass bucket scatter into padded regions ----------------
__global__ __launch_bounds__(256) void bucket_scatter_kernel(
    const int* __restrict__ src, const int* __restrict__ dst,
    int* __restrict__ bcnt, unsigned int* __restrict__ packed, int E, int NBb)
{
    __shared__ int hist[MAXNB];
    __shared__ int sbase[MAXNB];
    for (int i = threadIdx.x; i < NBb; i += 256) hist[i] = 0;
    __syncthreads();
    int start = blockIdx.x * blockDim.x + threadIdx.x;
    int stride = gridDim.x * blockDim.x;
    for (int e = start; e < E; e += stride)
        atomicAdd(&hist[dst[e] >> 8], 1);          // LDS int atomic: native, on-CU
    __syncthreads();
    for (int i = threadIdx.x; i < NBb; i += 256) {
        int v = hist[i];
        sbase[i] = v ? (i * CAP + atomicAdd(&bcnt[i], v)) : 0;
    }
    __syncthreads();
    for (int i = threadIdx.x; i < NBb; i += 256) hist[i] = 0;  // reuse as cursor
    __syncthreads();
    for (int e = start; e < E; e += stride) {
        int d = dst[e];
        int b = d >> 8;
        int r = atomicAdd(&hist[b], 1);            // LDS rank
        packed[sbase[b] + r] = (unsigned)src[e] | ((unsigned)(d & 255) << 24);
    }
}

// ---------------- per-bucket CSR finalize (inline exclusive prefix of bcnt) ----------------
__global__ __launch_bounds__(256) void bucket_csr_kernel(
    const unsigned int* __restrict__ packed, const int* __restrict__ bcnt,
    int* __restrict__ ssrc, int* __restrict__ offs, int* __restrict__ ends, int N)
{
    __shared__ int hist[256], scan[256], cur[256];
    __shared__ int swbase;
    int b = blockIdx.x;
    int t = threadIdx.x;
    // exclusive prefix: wbase = sum_{i<b} bcnt[i]
    int partial = 0;
    for (int i = t; i < b; i += 256) partial += bcnt[i];
    scan[t] = partial;
    hist[t] = 0;
    __syncthreads();
    for (int d = 128; d > 0; d >>= 1) {
        if (t < d) scan[t] += scan[t + d];
        __syncthreads();
    }
    if (t == 0) swbase = scan[0];
    __syncthreads();
    int wbase = swbase;
    int cnt = bcnt[b];
    if (cnt > CAP) cnt = CAP;
    size_t rbase = (size_t)b * CAP;
    for (int i = t; i < cnt; i += 256)
        atomicAdd(&hist[packed[rbase + i] >> 24], 1);
    __syncthreads();
    int v = hist[t];
    scan[t] = v;
    __syncthreads();
    for (int d = 1; d < 256; d <<= 1) {
        int x = scan[t];
        int y = (t >= d) ? scan[t - d] : 0;
        __syncthreads();
        scan[t] = x + y;
        __syncthreads();
    }
    int e0 = wbase + scan[t] - v;
    cur[t] = e0;
    int node = b * 256 + t;
    if (node < N) { offs[node] = e0; ends[node] = e0 + v; }
    __syncthreads();
    for (int i = t; i < cnt; i += 256) {
        unsigned p = packed[rbase + i];
        int pos = atomicAdd(&cur[p >> 24], 1);
        ssrc[pos] = (int)(p & 0xFFFFFF);
    }
}

// ---------------- fused GIN layer: barrier-free, wave-owns-16-rows ----------------
__device__ inline void add4(float4& a, const float4& v) {
    a.x += v.x; a.y += v.y; a.z += v.z; a.w += v.w;
}

// accumulate 8 halves (16B) into two float4 accumulators
__device__ inline void cvt_acc(uint4 u, float4& a0, float4& a1) {
    __half2 h0 = __builtin_bit_cast(__half2, u.x);
    __half2 h1 = __builtin_bit_cast(__half2, u.y);
    __half2 h2 = __builtin_bit_cast(__half2, u.z);
    __half2 h3 = __builtin_bit_cast(__half2, u.w);
    float2 f0 = __half22float2(h0), f1 = __half22float2(h1);
    float2 f2 = __half22float2(h2), f3 = __half22float2(h3);
    a0.x += f0.x; a0.y += f0.y; a0.z += f1.x; a0.w += f1.y;
    a1.x += f2.x; a1.y += f2.y; a1.z += f3.x; a1.w += f3.y;
}

__global__ __launch_bounds__(256, 7) void gin_layer_kernel(
    const __half* __restrict__ hin, __half* __restrict__ hout,
    float* __restrict__ jk, const __half* __restrict__ hbase,
    const int* __restrict__ offs, const int* __restrict__ ends,
    const int* __restrict__ ssrc,
    const _Float16* __restrict__ w1p, const _Float16* __restrict__ w2p,
    const float* __restrict__ b1f, const float* __restrict__ b2,
    int N, int L, int relu_out, int last)
{
    __shared__ float lds[64 * RS];       // 17408B: per-wave 16-row tile, reused pre->z->h
    __shared__ int ebuf_s[4 * EBUF];     // 5632B: per-wave edge-index prefetch
    int t = threadIdx.x;
    int lane = t & 63;
    int w = t >> 6;
    int row0 = blockIdx.x * 64;
    int wrow0 = row0 + w * 16;           // this wave's 16 rows
    if (wrow0 >= N) return;              // legal: no barriers anywhere in this kernel

    float* wtile = lds + (size_t)w * 16 * RS;
    int* ebuf = ebuf_s + w * EBUF;

    // ---- per-wave CSR offsets via shuffle broadcast (no sync) ----
    int offv = 0, endv = 0;
    if (lane < 16) {
        int node = wrow0 + lane;
        int cn = (node < N) ? node : (N - 1);
        offv = offs[cn];
        endv = ends[cn];
        if (node >= N) offv = endv;      // OOB rows -> empty
    }
    int begAll = __shfl(offv, 0, 64);
    int endAll = __shfl(endv, 15, 64);
    int cnt = endAll - begAll;

    // ---- prefetch this wave's contiguous edge-index slice into LDS (coalesced) ----
    bool useLds = (cnt <= EBUF);
    if (useLds) {
        for (int k = lane; k < cnt; k += 64) ebuf[k] = ssrc[begAll + k];
    }
    asm volatile("" ::: "memory");       // compiler fence; same-wave DS is in-order in HW
    auto eidx = [&](int pos) -> int {
        return useLds ? ebuf[pos - begAll] : ssrc[pos];
    };

    // ---- gather: 16 rows as 8 concurrent pairs; lane = (row-slot, 16B chunk) ----
    // 4 independent edge loads in flight per iteration; no cross-lane reduce.
    {
        int rslot = lane >> 3;   // 0..7
        int q = lane & 7;        // 16B chunk of the 128B row (8 halves)
        int nodeA = wrow0 + rslot;
        int nodeB = wrow0 + 8 + rslot;
        int begA = __shfl(offv, rslot, 64),     endA = __shfl(endv, rslot, 64);
        int begB = __shfl(offv, 8 + rslot, 64), endB = __shfl(endv, 8 + rslot, 64);

        float4 a0 = make_float4(0.f, 0.f, 0.f, 0.f);
        float4 a1 = make_float4(0.f, 0.f, 0.f, 0.f);
        float4 c0 = make_float4(0.f, 0.f, 0.f, 0.f);
        float4 c1 = make_float4(0.f, 0.f, 0.f, 0.f);
        if (nodeA < N) {
            uint4 u = *(const uint4*)(hin + (size_t)nodeA * NDIM + q * 8);
            cvt_acc(u, a0, a1);
        }
        if (nodeB < N) {
            uint4 u = *(const uint4*)(hin + (size_t)nodeB * NDIM + q * 8);
            cvt_acc(u, c0, c1);
        }
        int kA = begA, kB = begB;
        while (kA + 2 <= endA && kB + 2 <= endB) {
            int iA0 = eidx(kA), iA1 = eidx(kA + 1);
            int iB0 = eidx(kB), iB1 = eidx(kB + 1);
            uint4 uA0 = *(const uint4*)(hin + (size_t)iA0 * NDIM + q * 8);
            uint4 uA1 = *(const uint4*)(hin + (size_t)iA1 * NDIM + q * 8);
            uint4 uB0 = *(const uint4*)(hin + (size_t)iB0 * NDIM + q * 8);
            uint4 uB1 = *(const uint4*)(hin + (size_t)iB1 * NDIM + q * 8);
            cvt_acc(uA0, a0, a1);
            cvt_acc(uA1, a0, a1);
            cvt_acc(uB0, c0, c1);
            cvt_acc(uB1, c0, c1);
            kA += 2; kB += 2;
        }
        for (; kA < endA; ++kA) {
            uint4 u = *(const uint4*)(hin + (size_t)eidx(kA) * NDIM + q * 8);
            cvt_acc(u, a0, a1);
        }
        for (; kB < endB; ++kB) {
            uint4 u = *(const uint4*)(hin + (size_t)eidx(kB) * NDIM + q * 8);
            cvt_acc(u, c0, c1);
        }
        if (nodeA < N) {
            float* p = wtile + rslot * RS + q * 8;
            *(float4*)(p) = a0;
            *(float4*)(p + 4) = a1;
        }
        if (nodeB < N) {
            float* p = wtile + (8 + rslot) * RS + q * 8;
            *(float4*)(p) = c0;
            *(float4*)(p + 4) = c1;
        }
    }
    asm volatile("" ::: "memory");   // phase fence (same-wave DS is in-order in HW)

    // ---- MLP via MFMA, split-fp16 for ~fp32 accuracy ----
    // A: row=lane&15, k=4*(lane>>4)+j (+16*ks); B: col=lane&15, same k
    // C: row=(lane>>4)*4+reg, col=lane&15
    int lane15 = lane & 15;
    int lgrp = lane >> 4;
    const float* aRow = wtile + (size_t)lane15 * RS;
    const h4* W1 = (const h4*)w1p;
    const h4* W2 = (const h4*)w2p;
    f4v zero = {0.f, 0.f, 0.f, 0.f};
    f4v acc[4];

    // GEMM1: z = relu(pre @ W1f + b1f)
    #pragma unroll
    for (int ct = 0; ct < 4; ++ct) acc[ct] = zero;
    #pragma unroll
    for (int ks = 0; ks < 4; ++ks) {
        float4 av = *(const float4*)(aRow + ks * 16 + lgrp * 4);
        h4 ah, al;
        ah[0] = (_Float16)av.x; al[0] = (_Float16)(av.x - (float)ah[0]);
        ah[1] = (_Float16)av.y; al[1] = (_Float16)(av.y - (float)ah[1]);
        ah[2] = (_Float16)av.z; al[2] = (_Float16)(av.z - (float)ah[2]);
        ah[3] = (_Float16)av.w; al[3] = (_Float16)(av.w - (float)ah[3]);
        #pragma unroll
        for (int ct = 0; ct < 4; ++ct) {
            const h4* bp = W1 + (size_t)((ks * 4 + ct) * 64 + lane) * 2;
            h4 bh = bp[0], bl = bp[1];   // one dwordx4
            acc[ct] = __builtin_amdgcn_mfma_f32_16x16x16f16(ah, bh, acc[ct], 0, 0, 0);
            acc[ct] = __builtin_amdgcn_mfma_f32_16x16x16f16(al, bh, acc[ct], 0, 0, 0);
            acc[ct] = __builtin_amdgcn_mfma_f32_16x16x16f16(ah, bl, acc[ct], 0, 0, 0);
        }
    }
    asm volatile("" ::: "memory");
    #pragma unroll
    for (int ct = 0; ct < 4; ++ct) {
        int col = ct * 16 + lane15;
        float bb = b1f[col];
        #pragma unroll
        for (int i = 0; i < 4; ++i)
            wtile[(size_t)(lgrp * 4 + i) * RS + col] = fmaxf(acc[ct][i] + bb, 0.f);
    }
    asm volatile("" ::: "memory");

    // GEMM2: h = z @ W2 + b2 (+relu for non-final layers)
    #pragma unroll
    for (int ct = 0; ct < 4; ++ct) acc[ct] = zero;
    #pragma unroll
    for (int ks = 0; ks < 4; ++ks) {
        float4 av = *(const float4*)(aRow + ks * 16 + lgrp * 4);
        h4 ah, al;
        ah[0] = (_Float16)av.x; al[0] = (_Float16)(av.x - (float)ah[0]);
        ah[1] = (_Float16)av.y; al[1] = (_Float16)(av.y - (float)ah[1]);
        ah[2] = (_Float16)av.z; al[2] = (_Float16)(av.z - (float)ah[2]);
        ah[3] = (_Float16)av.w; al[3] = (_Float16)(av.w - (float)ah[3]);
        #pragma unroll
        for (int ct = 0; ct < 4; ++ct) {
            const h4* bp = W2 + (size_t)((ks * 4 + ct) * 64 + lane) * 2;
            h4 bh = bp[0], bl = bp[1];
            acc[ct] = __builtin_amdgcn_mfma_f32_16x16x16f16(ah, bh, acc[ct], 0, 0, 0);
            acc[ct] = __builtin_amdgcn_mfma_f32_16x16x16f16(al, bh, acc[ct], 0, 0, 0);
            acc[ct] = __builtin_amdgcn_mfma_f32_16x16x16f16(ah, bl, acc[ct], 0, 0, 0);
        }
    }
    asm volatile("" ::: "memory");
    #pragma unroll
    for (int ct = 0; ct < 4; ++ct) {
        int col = ct * 16 + lane15;
        float bb = b2[col];
        #pragma unroll
        for (int i = 0; i < 4; ++i) {
            float hv = acc[ct][i] + bb;
            if (relu_out) hv = fmaxf(hv, 0.f);
            wtile[(size_t)(lgrp * 4 + i) * RS + col] = hv;
        }
    }
    asm volatile("" ::: "memory");

    // ---- writeback ----
    // non-last layers: h -> fp16 buffer only (jk never touched).
    // last layer: jk = h_L + sum_{j=1..L-1} h_j (read back from fp16 buffers, L2-warm).
    size_t nstride = (size_t)N * NDIM;
    #pragma unroll
    for (int it = 0; it < 4; ++it) {
        int fl = it * 64 + lane;
        int r = fl >> 4, c4 = fl & 15;
        int grow = wrow0 + r;
        if (grow >= N) continue;
        const float* p = wtile + (size_t)r * RS + c4 * 4;
        float4 hv = make_float4(p[0], p[1], p[2], p[3]);
        if (!last) {
            __half2* dp = (__half2*)(hout + (size_t)grow * NDIM + c4 * 4);
            dp[0] = __floats2half2_rn(hv.x, hv.y);
            dp[1] = __floats2half2_rn(hv.z, hv.w);
        } else {
            for (int j = 1; j < L; ++j) {
                uint2 u = *(const uint2*)(hbase + (size_t)j * nstride
                                          + (size_t)grow * NDIM + c4 * 4);
                __half2 x0 = __builtin_bit_cast(__half2, u.x);
                __half2 x1 = __builtin_bit_cast(__half2, u.y);
                float2 f0 = __half22float2(x0), f1 = __half22float2(x1);
                hv.x += f0.x; hv.y += f0.y; hv.z += f1.x; hv.w += f1.y;
            }
            *(float4*)(jk + (size_t)grow * NDIM + c4 * 4) = hv;
        }
    }
}

extern "C" void kernel_launch(void* const* d_in, const int* in_sizes, int n_in,
                              void* d_out, int out_size, void* d_ws, size_t ws_size,
                              hipStream_t stream) {
    const float* x     = (const float*)d_in[0];
    const int*   src   = (const int*)  d_in[1];
    const int*   dst   = (const int*)  d_in[2];
    const float* W1    = (const float*)d_in[3];
    const float* b1    = (const float*)d_in[4];
    const float* gamma = (const float*)d_in[5];
    const float* beta  = (const float*)d_in[6];
    const float* mean  = (const float*)d_in[7];
    const float* var   = (const float*)d_in[8];
    const float* W2    = (const float*)d_in[9];
    const float* b2    = (const float*)d_in[10];

    int N = in_sizes[0] / NDIM;
    int E = in_sizes[1];
    int L = in_sizes[3] / (NDIM * NDIM);
    int NBb = (N + 255) >> 8;            // buckets of 256 nodes
    int n4 = N * NDIM / 4;
    float* out = (float*)d_out;
    size_t ns = (size_t)N * NDIM;

    char* w = (char*)d_ws;
    size_t off = 0;
    auto carve = [&](size_t bytes) -> void* {
        void* p = w + off;
        off += (bytes + 255) & ~(size_t)255;
        return p;
    };
    __half* h16     = (__half*)carve((size_t)(L + 1) * ns * 2);  // x16, h1..hL chain
    int*    ssrc    = (int*)   carve((size_t)E * 4);
    unsigned int* packed = (unsigned int*)carve((size_t)NBb * CAP * 4);
    int*    offs    = (int*)   carve((size_t)N * 4);
    int*    ends    = (int*)   carve((size_t)N * 4);
    int*    bcnt    = (int*)   carve((size_t)(MAXNB + 1) * 4);
    _Float16* Wpk   = (_Float16*)carve((size_t)L * 2 * 16 * 64 * 8 * 2);  // hi/lo packed frags
    float*  b1f     = (float*) carve((size_t)L * NDIM * 4);

    prep_kernel<<<2 * L + (n4 + 255) / 256, 256, 0, stream>>>(
        x, h16, n4, W1, b1, gamma, beta, mean, var, W2, Wpk, b1f, L,
        bcnt, NBb + 1);
    bucket_scatter_kernel<<<256, 256, 0, stream>>>(src, dst, bcnt, packed, E, NBb);
    bucket_csr_kernel<<<NBb, 256, 0, stream>>>(packed, bcnt, ssrc, offs, ends, N);

    for (int l = 0; l < L; ++l) {
        gin_layer_kernel<<<(N + 63) / 64, 256, 0, stream>>>(
            h16 + (size_t)l * ns, h16 + (size_t)(l + 1) * ns, out, h16,
            offs, ends, ssrc,
            Wpk + (size_t)(l * 2 + 0) * 16 * 64 * 8,
            Wpk + (size_t)(l * 2 + 1) * 16 * 64 * 8,
            b1f + (size_t)l * NDIM, b2 + (size_t)l * NDIM,
            N, L, (l < L - 1) ? 1 : 0, (l == L - 1) ? 1 : 0);
    }
}

// Round 7
// 232.913 us; speedup vs baseline: 6.4625x; 1.0495x over previous
//
#include <hip/hip_runtime.h>
#include <hip/hip_fp16.h>

#define NDIM 64
#define RS 68      // LDS row stride in floats: 16B-aligned rows
#define MAXNB 512  // supports N <= 131072 (bucket = dst>>8); this problem: N=100000 -> 391
#define CAP 6144   // padded per-bucket capacity (expected ~3072, +55 sigma headroom)
#define EBUF 352   // per-block LDS edge-index buffer (16 rows, mean 192 edges, +11 sigma)

typedef _Float16 h4 __attribute__((ext_vector_type(4)));
typedef float f4v __attribute__((ext_vector_type(4)));

// ---------------- prep: BN-fold + split-fp16 weight pack, x -> fp16, bcnt zero ----------------
// Wpk layout: [(l*2+m)][frag=ks*4+ct][lane][0..3]=hi j, [4..7]=lo j (halfs)
// frag element: k = ks*16 + (lane>>4)*4 + j, col = ct*16 + (lane&15)
__global__ __launch_bounds__(256) void prep_kernel(
    const float* __restrict__ x, __half* __restrict__ x16, int n4,
    const float* __restrict__ W1, const float* __restrict__ b1,
    const float* __restrict__ gamma, const float* __restrict__ beta,
    const float* __restrict__ mean, const float* __restrict__ var,
    const float* __restrict__ W2,
    _Float16* __restrict__ Wpk, float* __restrict__ b1f, int L,
    int* __restrict__ bcnt, int nbz)
{
    int bid = blockIdx.x;
    int t = threadIdx.x;
    if (bid < 2 * L) {
        if (bid == 0)
            for (int i = t; i < nbz; i += 256) bcnt[i] = 0;   // replaces hipMemsetAsync
        int l = bid >> 1, m = bid & 1;
        const float* Wsrc = (m == 0 ? W1 : W2) + (size_t)l * 4096;
        if (m == 0 && t < 64) {
            float s = gamma[l * 64 + t] * rsqrtf(var[l * 64 + t] + 1e-5f);
            b1f[l * 64 + t] = (b1[l * 64 + t] - mean[l * 64 + t]) * s + beta[l * 64 + t];
        }
        int lane = t & 63;
        int c16 = lane & 15, kq = lane >> 4;
        for (int it = 0; it < 4; ++it) {
            int frag = it * 4 + (t >> 6);
            int ks = frag >> 2, ct = frag & 3;
            int col = ct * 16 + c16;
            int k0 = ks * 16 + kq * 4;
            float s = 1.f;
            if (m == 0) s = gamma[l * 64 + col] * rsqrtf(var[l * 64 + col] + 1e-5f);
            _Float16* dstp = Wpk + (((size_t)(l * 2 + m) * 16 + frag) * 64 + lane) * 8;
            for (int j = 0; j < 4; ++j) {
                float wv = Wsrc[(size_t)(k0 + j) * 64 + col] * s;
                _Float16 hi = (_Float16)wv;
                dstp[j] = hi;
                dstp[4 + j] = (_Float16)(wv - (float)hi);
            }
        }
        return;
    }
    int tid = (bid - 2 * L) * 256 + t;
    if (tid >= n4) return;
    float4 v = *(const float4*)(x + (size_t)tid * 4);
    __half2* dp = (__half2*)(x16 + (size_t)tid * 4);
    dp[0] = __floats2half2_rn(v.x, v.y);
    dp[1] = __floats2half2_rn(v.z, v.w);
}

// ---------------- single-pass bucket scatter into padded regions ----------------
__global__ __launch_bounds__(256) void bucket_scatter_kernel(
    const int* __restrict__ src, const int* __restrict__ dst,
    int* __restrict__ bcnt, unsigned int* __restrict__ packed, int E, int NBb)
{
    __shared__ int hist[MAXNB];
    __shared__ int sbase[MAXNB];
    for (int i = threadIdx.x; i < NBb; i += 256) hist[i] = 0;
    __syncthreads();
    int start = blockIdx.x * blockDim.x + threadIdx.x;
    int stride = gridDim.x * blockDim.x;
    for (int e = start; e < E; e += stride)
        atomicAdd(&hist[dst[e] >> 8], 1);          // LDS int atomic: native, on-CU
    __syncthreads();
    for (int i = threadIdx.x; i < NBb; i += 256) {
        int v = hist[i];
        sbase[i] = v ? (i * CAP + atomicAdd(&bcnt[i], v)) : 0;
    }
    __syncthreads();
    for (int i = threadIdx.x; i < NBb; i += 256) hist[i] = 0;  // reuse as cursor
    __syncthreads();
    for (int e = start; e < E; e += stride) {
        int d = dst[e];
        int b = d >> 8;
        int r = atomicAdd(&hist[b], 1);            // LDS rank
        packed[sbase[b] + r] = (unsigned)src[e] | ((unsigned)(d & 255) << 24);
    }
}

// ---------------- per-bucket CSR finalize (inline exclusive prefix of bcnt) ----------------
__global__ __launch_bounds__(256) void bucket_csr_kernel(
    const unsigned int* __restrict__ packed, const int* __restrict__ bcnt,
    int* __restrict__ ssrc, int* __restrict__ offs, int* __restrict__ ends, int N)
{
    __shared__ int hist[256], scan[256], cur[256];
    __shared__ int swbase;
    int b = blockIdx.x;
    int t = threadIdx.x;
    // exclusive prefix: wbase = sum_{i<b} bcnt[i]
    int partial = 0;
    for (int i = t; i < b; i += 256) partial += bcnt[i];
    scan[t] = partial;
    hist[t] = 0;
    __syncthreads();
    for (int d = 128; d > 0; d >>= 1) {
        if (t < d) scan[t] += scan[t + d];
        __syncthreads();
    }
    if (t == 0) swbase = scan[0];
    __syncthreads();
    int wbase = swbase;
    int cnt = bcnt[b];
    if (cnt > CAP) cnt = CAP;
    size_t rbase = (size_t)b * CAP;
    for (int i = t; i < cnt; i += 256)
        atomicAdd(&hist[packed[rbase + i] >> 24], 1);
    __syncthreads();
    int v = hist[t];
    scan[t] = v;
    __syncthreads();
    for (int d = 1; d < 256; d <<= 1) {
        int x = scan[t];
        int y = (t >= d) ? scan[t - d] : 0;
        __syncthreads();
        scan[t] = x + y;
        __syncthreads();
    }
    int e0 = wbase + scan[t] - v;
    cur[t] = e0;
    int node = b * 256 + t;
    if (node < N) { offs[node] = e0; ends[node] = e0 + v; }
    __syncthreads();
    for (int i = t; i < cnt; i += 256) {
        unsigned p = packed[rbase + i];
        int pos = atomicAdd(&cur[p >> 24], 1);
        ssrc[pos] = (int)(p & 0xFFFFFF);
    }
}

// ---------------- fused GIN layer: one wave per block, block owns 16 rows ----------------
// Regrid rationale: 4-wave/64-row blocks gave grid-limited 41.5% occupancy
// (1563 blocks / 256 CU = 6.1/CU). 1-wave blocks pack 28/CU by LDS (5.8KB).
__device__ inline void add4(float4& a, const float4& v) {
    a.x += v.x; a.y += v.y; a.z += v.z; a.w += v.w;
}

// accumulate 8 halves (16B) into two float4 accumulators
__device__ inline void cvt_acc(uint4 u, float4& a0, float4& a1) {
    __half2 h0 = __builtin_bit_cast(__half2, u.x);
    __half2 h1 = __builtin_bit_cast(__half2, u.y);
    __half2 h2 = __builtin_bit_cast(__half2, u.z);
    __half2 h3 = __builtin_bit_cast(__half2, u.w);
    float2 f0 = __half22float2(h0), f1 = __half22float2(h1);
    float2 f2 = __half22float2(h2), f3 = __half22float2(h3);
    a0.x += f0.x; a0.y += f0.y; a0.z += f1.x; a0.w += f1.y;
    a1.x += f2.x; a1.y += f2.y; a1.z += f3.x; a1.w += f3.y;
}

__global__ __launch_bounds__(64, 7) void gin_layer_kernel(
    const __half* __restrict__ hin, __half* __restrict__ hout,
    float* __restrict__ jk, const __half* __restrict__ hbase,
    const int* __restrict__ offs, const int* __restrict__ ends,
    const int* __restrict__ ssrc,
    const _Float16* __restrict__ w1p, const _Float16* __restrict__ w2p,
    const float* __restrict__ b1f, const float* __restrict__ b2,
    int N, int L, int relu_out, int last)
{
    __shared__ float wtile[16 * RS];     // 4352B: 16-row tile, reused pre->z->h
    __shared__ int ebuf[EBUF];           // 1408B: edge-index prefetch
    int lane = threadIdx.x;
    int wrow0 = blockIdx.x * 16;         // this block's 16 rows
    if (wrow0 >= N) return;              // no barriers anywhere in this kernel

    // ---- CSR offsets via shuffle broadcast (no sync) ----
    int offv = 0, endv = 0;
    if (lane < 16) {
        int node = wrow0 + lane;
        int cn = (node < N) ? node : (N - 1);
        offv = offs[cn];
        endv = ends[cn];
        if (node >= N) offv = endv;      // OOB rows -> empty
    }
    int begAll = __shfl(offv, 0, 64);
    int endAll = __shfl(endv, 15, 64);
    int cnt = endAll - begAll;

    // ---- prefetch this block's contiguous edge-index slice into LDS (coalesced) ----
    bool useLds = (cnt <= EBUF);
    if (useLds) {
        for (int k = lane; k < cnt; k += 64) ebuf[k] = ssrc[begAll + k];
    }
    asm volatile("" ::: "memory");       // compiler fence; same-wave DS is in-order in HW
    auto eidx = [&](int pos) -> int {
        return useLds ? ebuf[pos - begAll] : ssrc[pos];
    };

    // ---- gather: 16 rows as 8 concurrent pairs; lane = (row-slot, 16B chunk) ----
    // 4-wide joint unroll: up to 8 independent edge loads in flight per lane.
    {
        int rslot = lane >> 3;   // 0..7
        int q = lane & 7;        // 16B chunk of the 128B row (8 halves)
        int nodeA = wrow0 + rslot;
        int nodeB = wrow0 + 8 + rslot;
        int begA = __shfl(offv, rslot, 64),     endA = __shfl(endv, rslot, 64);
        int begB = __shfl(offv, 8 + rslot, 64), endB = __shfl(endv, 8 + rslot, 64);

        float4 a0 = make_float4(0.f, 0.f, 0.f, 0.f);
        float4 a1 = make_float4(0.f, 0.f, 0.f, 0.f);
        float4 c0 = make_float4(0.f, 0.f, 0.f, 0.f);
        float4 c1 = make_float4(0.f, 0.f, 0.f, 0.f);
        if (nodeA < N) {
            uint4 u = *(const uint4*)(hin + (size_t)nodeA * NDIM + q * 8);
            cvt_acc(u, a0, a1);
        }
        if (nodeB < N) {
            uint4 u = *(const uint4*)(hin + (size_t)nodeB * NDIM + q * 8);
            cvt_acc(u, c0, c1);
        }
        int kA = begA, kB = begB;
        while (kA + 4 <= endA && kB + 4 <= endB) {
            int iA0 = eidx(kA), iA1 = eidx(kA + 1), iA2 = eidx(kA + 2), iA3 = eidx(kA + 3);
            int iB0 = eidx(kB), iB1 = eidx(kB + 1), iB2 = eidx(kB + 2), iB3 = eidx(kB + 3);
            uint4 uA0 = *(const uint4*)(hin + (size_t)iA0 * NDIM + q * 8);
            uint4 uA1 = *(const uint4*)(hin + (size_t)iA1 * NDIM + q * 8);
            uint4 uA2 = *(const uint4*)(hin + (size_t)iA2 * NDIM + q * 8);
            uint4 uA3 = *(const uint4*)(hin + (size_t)iA3 * NDIM + q * 8);
            uint4 uB0 = *(const uint4*)(hin + (size_t)iB0 * NDIM + q * 8);
            uint4 uB1 = *(const uint4*)(hin + (size_t)iB1 * NDIM + q * 8);
            uint4 uB2 = *(const uint4*)(hin + (size_t)iB2 * NDIM + q * 8);
            uint4 uB3 = *(const uint4*)(hin + (size_t)iB3 * NDIM + q * 8);
            cvt_acc(uA0, a0, a1); cvt_acc(uA1, a0, a1);
            cvt_acc(uA2, a0, a1); cvt_acc(uA3, a0, a1);
            cvt_acc(uB0, c0, c1); cvt_acc(uB1, c0, c1);
            cvt_acc(uB2, c0, c1); cvt_acc(uB3, c0, c1);
            kA += 4; kB += 4;
        }
        for (; kA + 2 <= endA; kA += 2) {
            int i0 = eidx(kA), i1 = eidx(kA + 1);
            uint4 u0 = *(const uint4*)(hin + (size_t)i0 * NDIM + q * 8);
            uint4 u1 = *(const uint4*)(hin + (size_t)i1 * NDIM + q * 8);
            cvt_acc(u0, a0, a1);
            cvt_acc(u1, a0, a1);
        }
        if (kA < endA) {
            uint4 u = *(const uint4*)(hin + (size_t)eidx(kA) * NDIM + q * 8);
            cvt_acc(u, a0, a1);
        }
        for (; kB + 2 <= endB; kB += 2) {
            int i0 = eidx(kB), i1 = eidx(kB + 1);
            uint4 u0 = *(const uint4*)(hin + (size_t)i0 * NDIM + q * 8);
            uint4 u1 = *(const uint4*)(hin + (size_t)i1 * NDIM + q * 8);
            cvt_acc(u0, c0, c1);
            cvt_acc(u1, c0, c1);
        }
        if (kB < endB) {
            uint4 u = *(const uint4*)(hin + (size_t)eidx(kB) * NDIM + q * 8);
            cvt_acc(u, c0, c1);
        }
        if (nodeA < N) {
            float* p = wtile + rslot * RS + q * 8;
            *(float4*)(p) = a0;
            *(float4*)(p + 4) = a1;
        }
        if (nodeB < N) {
            float* p = wtile + (8 + rslot) * RS + q * 8;
            *(float4*)(p) = c0;
            *(float4*)(p + 4) = c1;
        }
    }
    asm volatile("" ::: "memory");   // phase fence (same-wave DS is in-order in HW)

    // ---- MLP via MFMA, split-fp16 for ~fp32 accuracy ----
    // A: row=lane&15, k=4*(lane>>4)+j (+16*ks); B: col=lane&15, same k
    // C: row=(lane>>4)*4+reg, col=lane&15
    int lane15 = lane & 15;
    int lgrp = lane >> 4;
    const float* aRow = wtile + (size_t)lane15 * RS;
    const h4* W1 = (const h4*)w1p;
    const h4* W2 = (const h4*)w2p;
    f4v zero = {0.f, 0.f, 0.f, 0.f};
    f4v acc[4];

    // GEMM1: z = relu(pre @ W1f + b1f)
    #pragma unroll
    for (int ct = 0; ct < 4; ++ct) acc[ct] = zero;
    #pragma unroll
    for (int ks = 0; ks < 4; ++ks) {
        float4 av = *(const float4*)(aRow + ks * 16 + lgrp * 4);
        h4 ah, al;
        ah[0] = (_Float16)av.x; al[0] = (_Float16)(av.x - (float)ah[0]);
        ah[1] = (_Float16)av.y; al[1] = (_Float16)(av.y - (float)ah[1]);
        ah[2] = (_Float16)av.z; al[2] = (_Float16)(av.z - (float)ah[2]);
        ah[3] = (_Float16)av.w; al[3] = (_Float16)(av.w - (float)ah[3]);
        #pragma unroll
        for (int ct = 0; ct < 4; ++ct) {
            const h4* bp = W1 + (size_t)((ks * 4 + ct) * 64 + lane) * 2;
            h4 bh = bp[0], bl = bp[1];   // one dwordx4
            acc[ct] = __builtin_amdgcn_mfma_f32_16x16x16f16(ah, bh, acc[ct], 0, 0, 0);
            acc[ct] = __builtin_amdgcn_mfma_f32_16x16x16f16(al, bh, acc[ct], 0, 0, 0);
            acc[ct] = __builtin_amdgcn_mfma_f32_16x16x16f16(ah, bl, acc[ct], 0, 0, 0);
        }
    }
    asm volatile("" ::: "memory");
    #pragma unroll
    for (int ct = 0; ct < 4; ++ct) {
        int col = ct * 16 + lane15;
        float bb = b1f[col];
        #pragma unroll
        for (int i = 0; i < 4; ++i)
            wtile[(size_t)(lgrp * 4 + i) * RS + col] = fmaxf(acc[ct][i] + bb, 0.f);
    }
    asm volatile("" ::: "memory");

    // GEMM2: h = z @ W2 + b2 (+relu for non-final layers)
    #pragma unroll
    for (int ct = 0; ct < 4; ++ct) acc[ct] = zero;
    #pragma unroll
    for (int ks = 0; ks < 4; ++ks) {
        float4 av = *(const float4*)(aRow + ks * 16 + lgrp * 4);
        h4 ah, al;
        ah[0] = (_Float16)av.x; al[0] = (_Float16)(av.x - (float)ah[0]);
        ah[1] = (_Float16)av.y; al[1] = (_Float16)(av.y - (float)ah[1]);
        ah[2] = (_Float16)av.z; al[2] = (_Float16)(av.z - (float)ah[2]);
        ah[3] = (_Float16)av.w; al[3] = (_Float16)(av.w - (float)ah[3]);
        #pragma unroll
        for (int ct = 0; ct < 4; ++ct) {
            const h4* bp = W2 + (size_t)((ks * 4 + ct) * 64 + lane) * 2;
            h4 bh = bp[0], bl = bp[1];
            acc[ct] = __builtin_amdgcn_mfma_f32_16x16x16f16(ah, bh, acc[ct], 0, 0, 0);
            acc[ct] = __builtin_amdgcn_mfma_f32_16x16x16f16(al, bh, acc[ct], 0, 0, 0);
            acc[ct] = __builtin_amdgcn_mfma_f32_16x16x16f16(ah, bl, acc[ct], 0, 0, 0);
        }
    }
    asm volatile("" ::: "memory");
    #pragma unroll
    for (int ct = 0; ct < 4; ++ct) {
        int col = ct * 16 + lane15;
        float bb = b2[col];
        #pragma unroll
        for (int i = 0; i < 4; ++i) {
            float hv = acc[ct][i] + bb;
            if (relu_out) hv = fmaxf(hv, 0.f);
            wtile[(size_t)(lgrp * 4 + i) * RS + col] = hv;
        }
    }
    asm volatile("" ::: "memory");

    // ---- writeback ----
    // non-last layers: h -> fp16 buffer only (jk never touched).
    // last layer: jk = h_L + sum_{j=1..L-1} h_j (read back from fp16 buffers, L2/L3-warm).
    size_t nstride = (size_t)N * NDIM;
    #pragma unroll
    for (int it = 0; it < 4; ++it) {
        int fl = it * 64 + lane;
        int r = fl >> 4, c4 = fl & 15;
        int grow = wrow0 + r;
        if (grow >= N) continue;
        const float* p = wtile + (size_t)r * RS + c4 * 4;
        float4 hv = make_float4(p[0], p[1], p[2], p[3]);
        if (!last) {
            __half2* dp = (__half2*)(hout + (size_t)grow * NDIM + c4 * 4);
            dp[0] = __floats2half2_rn(hv.x, hv.y);
            dp[1] = __floats2half2_rn(hv.z, hv.w);
        } else {
            for (int j = 1; j < L; ++j) {
                uint2 u = *(const uint2*)(hbase + (size_t)j * nstride
                                          + (size_t)grow * NDIM + c4 * 4);
                __half2 x0 = __builtin_bit_cast(__half2, u.x);
                __half2 x1 = __builtin_bit_cast(__half2, u.y);
                float2 f0 = __half22float2(x0), f1 = __half22float2(x1);
                hv.x += f0.x; hv.y += f0.y; hv.z += f1.x; hv.w += f1.y;
            }
            *(float4*)(jk + (size_t)grow * NDIM + c4 * 4) = hv;
        }
    }
}

extern "C" void kernel_launch(void* const* d_in, const int* in_sizes, int n_in,
                              void* d_out, int out_size, void* d_ws, size_t ws_size,
                              hipStream_t stream) {
    const float* x     = (const float*)d_in[0];
    const int*   src   = (const int*)  d_in[1];
    const int*   dst   = (const int*)  d_in[2];
    const float* W1    = (const float*)d_in[3];
    const float* b1    = (const float*)d_in[4];
    const float* gamma = (const float*)d_in[5];
    const float* beta  = (const float*)d_in[6];
    const float* mean  = (const float*)d_in[7];
    const float* var   = (const float*)d_in[8];
    const float* W2    = (const float*)d_in[9];
    const float* b2    = (const float*)d_in[10];

    int N = in_sizes[0] / NDIM;
    int E = in_sizes[1];
    int L = in_sizes[3] / (NDIM * NDIM);
    int NBb = (N + 255) >> 8;            // buckets of 256 nodes
    int n4 = N * NDIM / 4;
    float* out = (float*)d_out;
    size_t ns = (size_t)N * NDIM;

    char* w = (char*)d_ws;
    size_t off = 0;
    auto carve = [&](size_t bytes) -> void* {
        void* p = w + off;
        off += (bytes + 255) & ~(size_t)255;
        return p;
    };
    __half* h16     = (__half*)carve((size_t)(L + 1) * ns * 2);  // x16, h1..hL chain
    int*    ssrc    = (int*)   carve((size_t)E * 4);
    unsigned int* packed = (unsigned int*)carve((size_t)NBb * CAP * 4);
    int*    offs    = (int*)   carve((size_t)N * 4);
    int*    ends    = (int*)   carve((size_t)N * 4);
    int*    bcnt    = (int*)   carve((size_t)(MAXNB + 1) * 4);
    _Float16* Wpk   = (_Float16*)carve((size_t)L * 2 * 16 * 64 * 8 * 2);  // hi/lo packed frags
    float*  b1f     = (float*) carve((size_t)L * NDIM * 4);

    prep_kernel<<<2 * L + (n4 + 255) / 256, 256, 0, stream>>>(
        x, h16, n4, W1, b1, gamma, beta, mean, var, W2, Wpk, b1f, L,
        bcnt, NBb + 1);
    bucket_scatter_kernel<<<256, 256, 0, stream>>>(src, dst, bcnt, packed, E, NBb);
    bucket_csr_kernel<<<NBb, 256, 0, stream>>>(packed, bcnt, ssrc, offs, ends, N);

    int NB16 = (N + 15) / 16;
    for (int l = 0; l < L; ++l) {
        gin_layer_kernel<<<NB16, 64, 0, stream>>>(
            h16 + (size_t)l * ns, h16 + (size_t)(l + 1) * ns, out, h16,
            offs, ends, ssrc,
            Wpk + (size_t)(l * 2 + 0) * 16 * 64 * 8,
            Wpk + (size_t)(l * 2 + 1) * 16 * 64 * 8,
            b1f + (size_t)l * NDIM, b2 + (size_t)l * NDIM,
            N, L, (l < L - 1) ? 1 : 0, (l == L - 1) ? 1 : 0);
    }
}